// Round 3
// baseline (7555.839 us; speedup 1.0000x reference)
//
#include <hip/hip_runtime.h>
#include <hip/hip_bf16.h>
#include <cstdint>
#include <cstddef>

#define H 128

using f32x4v = __attribute__((ext_vector_type(4))) float;
using bf8 = __attribute__((ext_vector_type(8))) short;

__device__ __forceinline__ short f2bf(float f) {
  unsigned u = __float_as_uint(f);
  u = (u + 0x7fffu + ((u >> 16) & 1u)) >> 16;
  return (short)u;
}
__device__ __forceinline__ float bf2f(short h) {
  return __uint_as_float(((unsigned)(unsigned short)h) << 16);
}
__device__ __forceinline__ void splitf(float f, short& h, short& l) {
  h = f2bf(f);
  l = f2bf(f - bf2f(h));
}
__device__ __forceinline__ f32x4v mfma16(bf8 a, bf8 b, f32x4v c) {
  return __builtin_amdgcn_mfma_f32_16x16x32_bf16(a, b, c, 0, 0, 0);
}

// ---------------- weight packing into MFMA b-frag layout ----------------
// W[k][n] -> frag idx = ((nt*(K/32)+ks)*512 + lane*8 + b), lane=(n&15)|((kk>>3)<<4), b=kk&7

__global__ __launch_bounds__(256) void pack_w_k(const float* __restrict__ W,
    short* __restrict__ hi, short* __restrict__ lo, int K, int N) {
  int total = K * N;
  int t = blockIdx.x * 256 + threadIdx.x;
  int layer = blockIdx.y;
  if (t >= total) return;
  int k = t / N, n = t - k * N;
  float f = W[(size_t)layer * total + t];
  short h, l; splitf(f, h, l);
  int nt = n >> 4, ks = k >> 5, kk = k & 31;
  int lane = (n & 15) | (((kk >> 3) & 3) << 4);
  size_t idx = (size_t)layer * total + ((size_t)(nt * (K >> 5) + ks) << 9) + lane * 8 + (kk & 7);
  hi[idx] = h; lo[idx] = l;
}

// ---------------- embedding / init ----------------

__global__ __launch_bounds__(256) void atom_encode_k(const int* __restrict__ nf,
    const float* __restrict__ emb, float* __restrict__ x, float* __restrict__ abuf, int N) {
  long long t = (long long)blockIdx.x * 256 + threadIdx.x;
  if (t >= (long long)N * H) return;
  int n = (int)(t >> 7), h = (int)(t & 127);
  const int* row = nf + (size_t)n * 9;
  float s = 0.f;
#pragma unroll
  for (int f = 0; f < 9; ++f) s += emb[((size_t)f * 100 + row[f]) * H + h];
  x[t] = s;
  abuf[t] = s;
}

__global__ __launch_bounds__(256) void rg_init_k(const int* __restrict__ feat,
    const float* __restrict__ emb, float* __restrict__ rg, int NRG) {
  long long t = (long long)blockIdx.x * 256 + threadIdx.x;
  if (t >= (long long)NRG * H) return;
  int n = (int)(t >> 7), h = (int)(t & 127);
  rg[t] = emb[(size_t)feat[n] * H + h];
}

// ---------------- edge message + scatter ----------------

__global__ __launch_bounds__(256) void edge_msg_k(const int* __restrict__ ei,
    const int* __restrict__ ef, const float* __restrict__ bemb,
    const float* __restrict__ x, float* __restrict__ abuf, int E) {
  long long t = (long long)blockIdx.x * 256 + threadIdx.x;
  if (t >= (long long)E * H) return;
  int e = (int)(t >> 7), h = (int)(t & 127);
  int src = ei[e], dst = ei[(size_t)E + e];
  const int* f = ef + (size_t)e * 3;
  float v = bemb[(size_t)f[0] * H + h]
          + bemb[((size_t)100 + f[1]) * H + h]
          + bemb[((size_t)200 + f[2]) * H + h];
  float m = fmaxf(x[(size_t)src * H + h] + v, 0.f);
  atomicAdd(&abuf[(size_t)dst * H + h], m);
}

__global__ __launch_bounds__(256) void scatter_add_k(const int* __restrict__ sidx,
    const int* __restrict__ didx, const float* __restrict__ src,
    float* __restrict__ dst, int M) {
  long long t = (long long)blockIdx.x * 256 + threadIdx.x;
  if (t >= (long long)M * H) return;
  int m = (int)(t >> 7), h = (int)(t & 127);
  int sr = sidx ? sidx[m] : m;
  atomicAdd(&dst[(size_t)didx[m] * H + h], src[(size_t)sr * H + h]);
}

// ---------------- counts ----------------

__global__ __launch_bounds__(256) void count_k(const int* __restrict__ idx,
    float* __restrict__ cnt, int n) {
  int t = blockIdx.x * 256 + threadIdx.x;
  if (t < n) atomicAdd(&cnt[idx[t]], 1.0f);
}

__global__ __launch_bounds__(256) void inv_k(float* v, int n) {
  int t = blockIdx.x * 256 + threadIdx.x;
  if (t < n) v[t] = 1.0f / fmaxf(v[t], 1.0f);
}

// ---------------- batchnorm helpers ----------------

__global__ void bn_final_k(const float* __restrict__ ssum, const float* __restrict__ ssq,
    float* __restrict__ mu, float* __restrict__ rsig, int C, float invM) {
  int c = threadIdx.x + blockIdx.x * blockDim.x;
  if (c < C) {
    float m = ssum[c] * invM;
    float v = ssq[c] * invM - m * m;
    mu[c] = m;
    rsig[c] = rsqrtf(v + 1e-5f);
  }
}

__global__ __launch_bounds__(256) void bn_apply_relu_k(const float* __restrict__ X,
    const float* __restrict__ mu, const float* __restrict__ rsig,
    float* __restrict__ Out, int M) {
  long long t = (long long)blockIdx.x * 256 + threadIdx.x;
  if (t >= (long long)M * 32) return;
  int c4 = ((int)(t & 31)) * 4;
  float4 v = ((const float4*)X)[t];
  float4 m4 = *(const float4*)&mu[c4];
  float4 r4 = *(const float4*)&rsig[c4];
  v.x = fmaxf((v.x - m4.x) * r4.x, 0.f);
  v.y = fmaxf((v.y - m4.y) * r4.y, 0.f);
  v.z = fmaxf((v.z - m4.z) * r4.z, 0.f);
  v.w = fmaxf((v.w - m4.w) * r4.w, 0.f);
  ((float4*)Out)[t] = v;
}

// ---------------- MFMA MLP stats: column sum/sumsq of A[M,128] @ W1[128,256] ----------------

__global__ __launch_bounds__(256) void mlp_stats_mfma_k(
    const float* __restrict__ A, const short* __restrict__ w1h, const short* __restrict__ w1l,
    float* __restrict__ ssum, float* __restrict__ ssq, int M, int ntiles) {
  __shared__ float sRed[256], qRed[256];
  int tid = threadIdx.x;
  sRed[tid] = 0.f; qRed[tid] = 0.f;
  __syncthreads();
  int w = tid >> 6, l = tid & 63, l15 = l & 15, lg = l >> 4;
  float sAcc[16], qAcc[16];
#pragma unroll
  for (int nt = 0; nt < 16; ++nt) { sAcc[nt] = 0.f; qAcc[nt] = 0.f; }
  for (int tb = blockIdx.x; tb < ntiles; tb += gridDim.x) {
    int arow = tb * 64 + w * 16 + l15;
    bool av = arow < M;
    bf8 ah[4], al_[4];
    const float* Ap = A + (size_t)arow * 128 + lg * 8;
#pragma unroll
    for (int ks = 0; ks < 4; ++ks) {
      float v[8];
      if (av) {
        f32x4v p0 = *(const f32x4v*)(Ap + ks * 32);
        f32x4v p1 = *(const f32x4v*)(Ap + ks * 32 + 4);
        v[0]=p0.x; v[1]=p0.y; v[2]=p0.z; v[3]=p0.w;
        v[4]=p1.x; v[5]=p1.y; v[6]=p1.z; v[7]=p1.w;
      } else {
#pragma unroll
        for (int j = 0; j < 8; ++j) v[j] = 0.f;
      }
#pragma unroll
      for (int j = 0; j < 8; ++j) { short hh, ll; splitf(v[j], hh, ll); ah[ks][j]=hh; al_[ks][j]=ll; }
    }
#pragma unroll
    for (int nt = 0; nt < 16; ++nt) {
      f32x4v c = {0.f, 0.f, 0.f, 0.f};
      const short* bph = w1h + ((size_t)(nt * 4) << 9) + l * 8;
      const short* bpl = w1l + ((size_t)(nt * 4) << 9) + l * 8;
#pragma unroll
      for (int ks = 0; ks < 4; ++ks) {
        bf8 bh = *(const bf8*)(bph + ks * 512);
        bf8 bl = *(const bf8*)(bpl + ks * 512);
        c = mfma16(al_[ks], bh, c);
        c = mfma16(ah[ks], bl, c);
        c = mfma16(ah[ks], bh, c);
      }
      float s = c[0] + c[1] + c[2] + c[3];
      float q = c[0]*c[0] + c[1]*c[1] + c[2]*c[2] + c[3]*c[3];
      sAcc[nt] += s; qAcc[nt] += q;
    }
  }
#pragma unroll
  for (int nt = 0; nt < 16; ++nt) {
    float s = sAcc[nt], q = qAcc[nt];
    s += __shfl_xor(s, 16); s += __shfl_xor(s, 32);
    q += __shfl_xor(q, 16); q += __shfl_xor(q, 32);
    if (l < 16) { atomicAdd(&sRed[nt * 16 + l], s); atomicAdd(&qRed[nt * 16 + l], q); }
  }
  __syncthreads();
  atomicAdd(&ssum[tid], sRed[tid]);
  atomicAdd(&ssq[tid], qRed[tid]);
}

// ---------------- MFMA fused MLP: A <- relu(BN1(A@W1))@W2 in-place, + BN2 col stats ----------------

__global__ __launch_bounds__(256) void mlp_fused_mfma_k(
    float* __restrict__ A, const short* __restrict__ w1h, const short* __restrict__ w1l,
    const short* __restrict__ w2h, const short* __restrict__ w2l,
    const float* __restrict__ mu, const float* __restrict__ rsig,
    float* __restrict__ ssum, float* __restrict__ ssq, int M, int ntiles) {
  __shared__ __align__(16) short Th[4][4096];  // [wave][ks2*512 + lane*8 + b]
  __shared__ __align__(16) short Tl[4][4096];
  __shared__ float sRed[128], qRed[128];
  int tid = threadIdx.x;
  if (tid < 128) { sRed[tid] = 0.f; qRed[tid] = 0.f; }
  __syncthreads();
  int w = tid >> 6, l = tid & 63, l15 = l & 15, lg = l >> 4;
  float sAcc[8], qAcc[8];
#pragma unroll
  for (int nt = 0; nt < 8; ++nt) { sAcc[nt] = 0.f; qAcc[nt] = 0.f; }
  for (int tb = blockIdx.x; tb < ntiles; tb += gridDim.x) {
    int arow = tb * 64 + w * 16 + l15;
    bool av = arow < M;
    // ---- stage 1 a-frags (hi/lo)
    bf8 ah[4], al_[4];
    const float* Ap = A + (size_t)arow * 128 + lg * 8;
#pragma unroll
    for (int ks = 0; ks < 4; ++ks) {
      float v[8];
      if (av) {
        f32x4v p0 = *(const f32x4v*)(Ap + ks * 32);
        f32x4v p1 = *(const f32x4v*)(Ap + ks * 32 + 4);
        v[0]=p0.x; v[1]=p0.y; v[2]=p0.z; v[3]=p0.w;
        v[4]=p1.x; v[5]=p1.y; v[6]=p1.z; v[7]=p1.w;
      } else {
#pragma unroll
        for (int j = 0; j < 8; ++j) v[j] = 0.f;
      }
#pragma unroll
      for (int j = 0; j < 8; ++j) { short hh, ll; splitf(v[j], hh, ll); ah[ks][j]=hh; al_[ks][j]=ll; }
    }
    // ---- stage 1 GEMM + BN1 + relu -> LDS (stage-2 a-frag layout), wave-local
#pragma unroll
    for (int nt = 0; nt < 16; ++nt) {
      f32x4v c = {0.f, 0.f, 0.f, 0.f};
      const short* bph = w1h + ((size_t)(nt * 4) << 9) + l * 8;
      const short* bpl = w1l + ((size_t)(nt * 4) << 9) + l * 8;
#pragma unroll
      for (int ks = 0; ks < 4; ++ks) {
        bf8 bh = *(const bf8*)(bph + ks * 512);
        bf8 bl = *(const bf8*)(bpl + ks * 512);
        c = mfma16(al_[ks], bh, c);
        c = mfma16(ah[ks], bl, c);
        c = mfma16(ah[ks], bh, c);
      }
      int cc = nt * 16 + l15;
      float mm = mu[cc], rs = rsig[cc];
      int qsel = ((cc >> 3) & 3) << 4;
      int idx0 = ((cc >> 5) << 9) + (cc & 7);
#pragma unroll
      for (int r = 0; r < 4; ++r) {
        float t = fmaxf((c[r] - mm) * rs, 0.f);
        short hh, ll; splitf(t, hh, ll);
        int lane2 = (lg * 4 + r) | qsel;
        int idx = idx0 + lane2 * 8;
        Th[w][idx] = hh;
        Tl[w][idx] = ll;
      }
    }
    // ---- stage 2: T[16,256] @ W2[256,128]  (wave reads only its own LDS region)
    f32x4v acc2[8];
#pragma unroll
    for (int nt = 0; nt < 8; ++nt) acc2[nt] = (f32x4v){0.f, 0.f, 0.f, 0.f};
#pragma unroll
    for (int ks = 0; ks < 8; ++ks) {
      bf8 a2h = *(const bf8*)&Th[w][ks * 512 + l * 8];
      bf8 a2l = *(const bf8*)&Tl[w][ks * 512 + l * 8];
      const short* b2h = w2h + ((size_t)ks << 9) + l * 8;
      const short* b2l = w2l + ((size_t)ks << 9) + l * 8;
#pragma unroll
      for (int nt = 0; nt < 8; ++nt) {
        bf8 bh = *(const bf8*)(b2h + ((size_t)(nt * 8) << 9));
        bf8 bl = *(const bf8*)(b2l + ((size_t)(nt * 8) << 9));
        acc2[nt] = mfma16(a2l, bh, acc2[nt]);
        acc2[nt] = mfma16(a2h, bl, acc2[nt]);
        acc2[nt] = mfma16(a2h, bh, acc2[nt]);
      }
    }
    // ---- epilogue: in-place write + BN2 stats
    int base = tb * 64 + w * 16;
#pragma unroll
    for (int nt = 0; nt < 8; ++nt) {
      int cc = nt * 16 + l15;
#pragma unroll
      for (int r = 0; r < 4; ++r) {
        int gr = base + lg * 4 + r;
        if (gr < M) {
          float vv = acc2[nt][r];
          A[(size_t)gr * 128 + cc] = vv;
          sAcc[nt] += vv;
          qAcc[nt] = fmaf(vv, vv, qAcc[nt]);
        }
      }
    }
  }
#pragma unroll
  for (int nt = 0; nt < 8; ++nt) {
    float s = sAcc[nt], q = qAcc[nt];
    s += __shfl_xor(s, 16); s += __shfl_xor(s, 32);
    q += __shfl_xor(q, 16); q += __shfl_xor(q, 32);
    if (l < 16) { atomicAdd(&sRed[nt * 16 + l], s); atomicAdd(&qRed[nt * 16 + l], q); }
  }
  __syncthreads();
  if (tid < 128) { atomicAdd(&ssum[tid], sRed[tid]); atomicAdd(&ssq[tid], qRed[tid]); }
}

// ---------------- MFMA 128x128 GEMM: Out=Out+relu((A*aux)@W); Out2=Out (W staged in LDS) ----------------

__global__ __launch_bounds__(256) void gemm128_mfma_k(
    const float* __restrict__ A0, const float* __restrict__ AUX,
    const short* __restrict__ wh, const short* __restrict__ wl,
    float* __restrict__ Out, float* __restrict__ Out2, int M, int ntiles) {
  __shared__ __align__(16) short Wh[16384], Wl[16384];
  int tid = threadIdx.x;
  for (int i = tid; i < 2048; i += 256) {
    ((f32x4v*)Wh)[i] = ((const f32x4v*)wh)[i];
    ((f32x4v*)Wl)[i] = ((const f32x4v*)wl)[i];
  }
  __syncthreads();
  int w = tid >> 6, l = tid & 63, l15 = l & 15, lg = l >> 4;
  for (int tb = blockIdx.x; tb < ntiles; tb += gridDim.x) {
    int arow = tb * 64 + w * 16 + l15;
    bool av = arow < M;
    float sc = av ? AUX[arow] : 0.f;
    bf8 ah[4], al_[4];
    const float* Ap = A0 + (size_t)arow * 128 + lg * 8;
#pragma unroll
    for (int ks = 0; ks < 4; ++ks) {
      float v[8];
      if (av) {
        f32x4v p0 = *(const f32x4v*)(Ap + ks * 32);
        f32x4v p1 = *(const f32x4v*)(Ap + ks * 32 + 4);
        v[0]=p0.x*sc; v[1]=p0.y*sc; v[2]=p0.z*sc; v[3]=p0.w*sc;
        v[4]=p1.x*sc; v[5]=p1.y*sc; v[6]=p1.z*sc; v[7]=p1.w*sc;
      } else {
#pragma unroll
        for (int j = 0; j < 8; ++j) v[j] = 0.f;
      }
#pragma unroll
      for (int j = 0; j < 8; ++j) { short hh, ll; splitf(v[j], hh, ll); ah[ks][j]=hh; al_[ks][j]=ll; }
    }
    int base = tb * 64 + w * 16;
#pragma unroll
    for (int nt = 0; nt < 8; ++nt) {
      f32x4v c = {0.f, 0.f, 0.f, 0.f};
#pragma unroll
      for (int ks = 0; ks < 4; ++ks) {
        bf8 bh = *(const bf8*)&Wh[(nt * 4 + ks) * 512 + l * 8];
        bf8 bl = *(const bf8*)&Wl[(nt * 4 + ks) * 512 + l * 8];
        c = mfma16(al_[ks], bh, c);
        c = mfma16(ah[ks], bl, c);
        c = mfma16(ah[ks], bh, c);
      }
#pragma unroll
      for (int r = 0; r < 4; ++r) {
        int gr = base + lg * 4 + r;
        if (gr < M) {
          size_t o = (size_t)gr * 128 + nt * 16 + l15;
          float t = Out[o] + fmaxf(c[r], 0.f);
          Out[o] = t;
          Out2[o] = t;
        }
      }
    }
  }
}

// ---------------- f32 GEMM for readout (small) ----------------
// PRO: 0 plain, 2 A*AUX[row]; EPI: 0 Out=acc, 2 Out=relu(Out+acc)
template<int PRO, int EPI>
__global__ __launch_bounds__(256) void gemm_k(
    const float* __restrict__ A0, const float* __restrict__ AUX,
    const float* __restrict__ W, float* __restrict__ Out, int M) {
  __shared__ __align__(16) float Ash[64][64];
  int tid = threadIdx.x;
  int tc = tid & 63, tr = tid >> 6;
  int row0 = blockIdx.x * 64;
  float acc[16][2];
#pragma unroll
  for (int i = 0; i < 16; ++i) { acc[i][0] = 0.f; acc[i][1] = 0.f; }
  for (int k0 = 0; k0 < 128; k0 += 64) {
#pragma unroll
    for (int it = 0; it < 4; ++it) {
      int fidx = tid + it * 256;
      int r = fidx >> 4, c4 = (fidx & 15) << 2;
      int gr = row0 + r;
      float4 v = make_float4(0.f, 0.f, 0.f, 0.f);
      if (gr < M) {
        v = *(const float4*)(A0 + (size_t)gr * 128 + k0 + c4);
        if (PRO == 2) { float s = AUX[gr]; v.x *= s; v.y *= s; v.z *= s; v.w *= s; }
      }
      *(float4*)&Ash[r][c4] = v;
    }
    __syncthreads();
    const float* Wp = W + (size_t)k0 * 128 + tc;
    for (int kk = 0; kk < 64; kk += 4) {
      float w[4][2];
#pragma unroll
      for (int kj = 0; kj < 4; ++kj)
#pragma unroll
        for (int j = 0; j < 2; ++j) w[kj][j] = Wp[(size_t)(kk + kj) * 128 + j * 64];
#pragma unroll
      for (int i = 0; i < 16; ++i) {
        float4 a = *(const float4*)&Ash[tr * 16 + i][kk];
#pragma unroll
        for (int j = 0; j < 2; ++j) {
          acc[i][j] = fmaf(a.x, w[0][j], acc[i][j]);
          acc[i][j] = fmaf(a.y, w[1][j], acc[i][j]);
          acc[i][j] = fmaf(a.z, w[2][j], acc[i][j]);
          acc[i][j] = fmaf(a.w, w[3][j], acc[i][j]);
        }
      }
    }
    __syncthreads();
  }
#pragma unroll
  for (int i = 0; i < 16; ++i) {
    int gr = row0 + tr * 16 + i;
    if (gr < M) {
#pragma unroll
      for (int j = 0; j < 2; ++j) {
        size_t o = (size_t)gr * 128 + tc + j * 64;
        float v = acc[i][j];
        if (EPI == 0) Out[o] = v;
        else Out[o] = fmaxf(Out[o] + v, 0.f);
      }
    }
  }
}

// ---------------- host ----------------

static inline int cdivll(long long a, long long b) { return (int)((a + b - 1) / b); }

extern "C" void kernel_launch(void* const* d_in, const int* in_sizes, int n_in,
                              void* d_out, int out_size, void* d_ws, size_t ws_size,
                              hipStream_t stream) {
  const int* node_feat  = (const int*)d_in[0];
  const int* edge_index = (const int*)d_in[1];
  const int* edge_feat  = (const int*)d_in[2];
  const int* batch      = (const int*)d_in[3];
  const int* map_row    = (const int*)d_in[4];
  const int* map_col    = (const int*)d_in[5];
  const int* rg_ei      = (const int*)d_in[6];
  const int* rg_feat    = (const int*)d_in[7];
  const int* tree_batch = (const int*)d_in[8];
  const float* atom_emb   = (const float*)d_in[10];
  const float* bond_emb   = (const float*)d_in[11];
  const float* rg_emb     = (const float*)d_in[12];
  const float* atom_W1    = (const float*)d_in[13];
  const float* atom_W2    = (const float*)d_in[14];
  const float* rg_W1      = (const float*)d_in[15];
  const float* rg_W2      = (const float*)d_in[16];
  const float* raw2rg_W   = (const float*)d_in[17];
  const float* rg2raw_W   = (const float*)d_in[18];
  const float* atom_lin_W = (const float*)d_in[19];
  const float* rg_lin_W   = (const float*)d_in[20];
  const float* lin_W      = (const float*)d_in[21];

  const int N   = in_sizes[0] / 9;
  const int E   = in_sizes[1] / 2;
  const int M   = in_sizes[4];
  const int NRG = in_sizes[7];
  const int ERG = in_sizes[6] / 2;
  const int G   = out_size / H;
  if (N <= 0 || G <= 0) return;

  const size_t NH = (size_t)N * H, RH = (size_t)NRG * H, GH = (size_t)G * H;
  const size_t need = 2 * NH + RH + (size_t)NRG + (size_t)N + 2 * (size_t)G + 1024 + 500000;
  if (ws_size < need * sizeof(float)) return;

  float* ws = (float*)d_ws;
  size_t off = 0;
  auto alloc = [&](size_t n) { float* p = ws + off; off += n; return p; };
  float* x    = alloc(NH);
  float* abuf = alloc(NH);
  float* rg   = alloc(RH);
  float* cnt_col   = alloc((size_t)NRG);
  float* cnt_row   = alloc((size_t)N);
  float* cnt_batch = alloc((size_t)G);
  float* cnt_tree  = alloc((size_t)G);
  float* ssum = alloc(256);
  float* ssq  = alloc(256);
  float* mu   = alloc(256);
  float* rsig = alloc(256);
  off = (off + 3) & ~(size_t)3;
  short* sp = (short*)(ws + off);
  size_t soff = 0;
  auto salloc = [&](size_t n) { short* p = sp + soff; soff += n; return p; };
  short* paW1h = salloc(3 * 32768); short* paW1l = salloc(3 * 32768);
  short* paW2h = salloc(3 * 32768); short* paW2l = salloc(3 * 32768);
  short* prW1h = salloc(3 * 32768); short* prW1l = salloc(3 * 32768);
  short* prW2h = salloc(3 * 32768); short* prW2l = salloc(3 * 32768);
  short* p2gh  = salloc(3 * 16384); short* p2gl  = salloc(3 * 16384);
  short* pg2h  = salloc(3 * 16384); short* pg2l  = salloc(3 * 16384);

  const int ta = (N + 63) >> 6, trg = (NRG + 63) >> 6;
  const int ga = ta < 512 ? ta : 512, grg = trg < 512 ? trg : 512;

  // ---- pack weights ----
  pack_w_k<<<dim3(128, 3), 256, 0, stream>>>(atom_W1, paW1h, paW1l, 128, 256);
  pack_w_k<<<dim3(128, 3), 256, 0, stream>>>(atom_W2, paW2h, paW2l, 256, 128);
  pack_w_k<<<dim3(128, 3), 256, 0, stream>>>(rg_W1, prW1h, prW1l, 128, 256);
  pack_w_k<<<dim3(128, 3), 256, 0, stream>>>(rg_W2, prW2h, prW2l, 256, 128);
  pack_w_k<<<dim3(64, 3), 256, 0, stream>>>(raw2rg_W, p2gh, p2gl, 128, 128);
  pack_w_k<<<dim3(64, 3), 256, 0, stream>>>(rg2raw_W, pg2h, pg2l, 128, 128);

  // ---- counts ----
  hipMemsetAsync(cnt_col, 0, (size_t)(NRG + N + 2 * G) * 4, stream);
  count_k<<<cdivll(M, 256), 256, 0, stream>>>(map_col, cnt_col, M);
  count_k<<<cdivll(M, 256), 256, 0, stream>>>(map_row, cnt_row, M);
  count_k<<<cdivll(N, 256), 256, 0, stream>>>(batch, cnt_batch, N);
  count_k<<<cdivll(NRG, 256), 256, 0, stream>>>(tree_batch, cnt_tree, NRG);
  inv_k<<<cdivll(NRG + N + 2 * G, 256), 256, 0, stream>>>(cnt_col, NRG + N + 2 * G);

  // ---- encoders ----
  atom_encode_k<<<cdivll(NH, 256), 256, 0, stream>>>(node_feat, atom_emb, x, abuf, N);
  rg_init_k<<<cdivll(RH, 256), 256, 0, stream>>>(rg_feat, rg_emb, rg, NRG);

  for (int i = 0; i < 3; ++i) {
    // --- GINE: abuf = x + agg ---
    edge_msg_k<<<cdivll((long long)E * H, 256), 256, 0, stream>>>(
        edge_index, edge_feat, bond_emb + (size_t)i * 3 * 100 * H, x, abuf, E);
    // --- atom MLP (MFMA) ---
    hipMemsetAsync(ssum, 0, 512 * 4, stream);
    mlp_stats_mfma_k<<<ga, 256, 0, stream>>>(abuf, paW1h + i * 32768, paW1l + i * 32768, ssum, ssq, N, ta);
    bn_final_k<<<1, 256, 0, stream>>>(ssum, ssq, mu, rsig, 256, 1.0f / N);
    hipMemsetAsync(ssum, 0, 512 * 4, stream);
    mlp_fused_mfma_k<<<ga, 256, 0, stream>>>(abuf, paW1h + i * 32768, paW1l + i * 32768,
        paW2h + i * 32768, paW2l + i * 32768, mu, rsig, ssum, ssq, N, ta);
    bn_final_k<<<1, 256, 0, stream>>>(ssum, ssq, mu, rsig, 128, 1.0f / N);
    bn_apply_relu_k<<<cdivll((long long)N * 32, 256), 256, 0, stream>>>(abuf, mu, rsig, x, N);

    // --- raw -> rg ---
    hipMemsetAsync(abuf, 0, RH * 4, stream);
    scatter_add_k<<<cdivll((long long)M * H, 256), 256, 0, stream>>>(map_row, map_col, x, abuf, M);
    gemm128_mfma_k<<<grg, 256, 0, stream>>>(abuf, cnt_col, p2gh + i * 16384, p2gl + i * 16384,
        rg, abuf, NRG, trg);

    // --- rg GIN ---
    scatter_add_k<<<cdivll((long long)ERG * H, 256), 256, 0, stream>>>(rg_ei, rg_ei + ERG, rg, abuf, ERG);
    hipMemsetAsync(ssum, 0, 512 * 4, stream);
    mlp_stats_mfma_k<<<grg, 256, 0, stream>>>(abuf, prW1h + i * 32768, prW1l + i * 32768, ssum, ssq, NRG, trg);
    bn_final_k<<<1, 256, 0, stream>>>(ssum, ssq, mu, rsig, 256, 1.0f / NRG);
    hipMemsetAsync(ssum, 0, 512 * 4, stream);
    mlp_fused_mfma_k<<<grg, 256, 0, stream>>>(abuf, prW1h + i * 32768, prW1l + i * 32768,
        prW2h + i * 32768, prW2l + i * 32768, mu, rsig, ssum, ssq, NRG, trg);
    bn_final_k<<<1, 256, 0, stream>>>(ssum, ssq, mu, rsig, 128, 1.0f / NRG);
    bn_apply_relu_k<<<cdivll((long long)NRG * 32, 256), 256, 0, stream>>>(abuf, mu, rsig, rg, NRG);

    // --- rg -> raw ---
    hipMemsetAsync(abuf, 0, NH * 4, stream);
    scatter_add_k<<<cdivll((long long)M * H, 256), 256, 0, stream>>>(map_col, map_row, rg, abuf, M);
    gemm128_mfma_k<<<ga, 256, 0, stream>>>(abuf, cnt_row, pg2h + i * 16384, pg2l + i * 16384,
        x, abuf, N, ta);
  }

  // ---- readout ----
  float* xg  = abuf;
  float* rgg = abuf + GH;
  float* P   = abuf + 2 * GH;
  hipMemsetAsync(abuf, 0, 2 * GH * 4, stream);
  scatter_add_k<<<cdivll(NH, 256), 256, 0, stream>>>(nullptr, batch, x, xg, N);
  scatter_add_k<<<cdivll(RH, 256), 256, 0, stream>>>(nullptr, tree_batch, rg, rgg, NRG);
  gemm_k<2, 0><<<cdivll(G, 64), 256, 0, stream>>>(xg, cnt_batch, atom_lin_W, P, G);
  gemm_k<2, 2><<<cdivll(G, 64), 256, 0, stream>>>(rgg, cnt_tree, rg_lin_W, P, G);
  gemm_k<0, 0><<<cdivll(G, 64), 256, 0, stream>>>(P, nullptr, lin_W, (float*)d_out, G);
}